// Round 2
// baseline (437.699 us; speedup 1.0000x reference)
//
#include <hip/hip_runtime.h>

typedef __bf16 bf16x8 __attribute__((ext_vector_type(8)));
typedef float f32x4 __attribute__((ext_vector_type(4)));

#define EMB 1024
#define CTXD 768
#define NH 16
#define HD 64
#define BB 8
#define NN 4096
#define MM 77
#define MPAD 96

static __device__ __forceinline__ unsigned short f2bf(float f) {
    unsigned u = __builtin_bit_cast(unsigned, f);
    u += 0x7FFFu + ((u >> 16) & 1u);
    return (unsigned short)(u >> 16);
}

// ---------------- mask layout detection + lengths ----------------
__global__ void mask_lengths_kernel(const unsigned char* __restrict__ mask,
                                    int* __restrict__ lengths) {
    __shared__ int layout; // 0=int32, 1=byte(bool), 2=float32
    if (threadIdx.x == 0) {
        int anyOdd = 0, anyF = 0;
        for (int i = 0; i < BB * MM; ++i) {
            unsigned char v = mask[i];
            if (v == 0x80u || v == 0x3Fu) anyF = 1;
            if ((i & 3) && v) anyOdd = 1;
        }
        layout = anyF ? 2 : (anyOdd ? 1 : 0);
    }
    __syncthreads();
    if (threadIdx.x < BB) {
        int b = threadIdx.x, cnt = 0, lay = layout;
        for (int m = 0; m < MM; ++m) {
            int idx = b * MM + m;
            int valid;
            if (lay == 1)      valid = mask[idx] != 0;
            else if (lay == 0) valid = ((const int*)mask)[idx] != 0;
            else               valid = ((const float*)mask)[idx] != 0.0f;
            cnt += valid ? 1 : 0;
        }
        lengths[b] = cnt;
    }
}

// ---------------- fp32 -> bf16 cast (8 elems/thread) ----------------
__global__ void cast_f32_to_bf16(const float* __restrict__ in,
                                 unsigned short* __restrict__ out, int n8) {
    for (int i = blockIdx.x * blockDim.x + threadIdx.x; i < n8;
         i += gridDim.x * blockDim.x) {
        float4 v0 = ((const float4*)in)[2 * i];
        float4 v1 = ((const float4*)in)[2 * i + 1];
        union { unsigned short u[8]; int4 v; } r;
        r.u[0] = f2bf(v0.x); r.u[1] = f2bf(v0.y);
        r.u[2] = f2bf(v0.z); r.u[3] = f2bf(v0.w);
        r.u[4] = f2bf(v1.x); r.u[5] = f2bf(v1.y);
        r.u[6] = f2bf(v1.z); r.u[7] = f2bf(v1.w);
        ((int4*)out)[i] = r.v;
    }
}

// ---------------- context cast with zero pad to 640 rows ----------------
__global__ void cast_ctx_kernel(const float* __restrict__ in,
                                unsigned short* __restrict__ out) {
    int i = blockIdx.x * 256 + threadIdx.x; // over 640*768/8 chunks
    if (i >= 640 * CTXD / 8) return;
    int e0 = i * 8;
    int row = e0 / CTXD;
    union { unsigned short u[8]; int4 v; } r;
    if (row < BB * MM) {
        float4 v0 = ((const float4*)in)[2 * i];
        float4 v1 = ((const float4*)in)[2 * i + 1];
        r.u[0] = f2bf(v0.x); r.u[1] = f2bf(v0.y);
        r.u[2] = f2bf(v0.z); r.u[3] = f2bf(v0.w);
        r.u[4] = f2bf(v1.x); r.u[5] = f2bf(v1.y);
        r.u[6] = f2bf(v1.z); r.u[7] = f2bf(v1.w);
    } else {
        r.v = make_int4(0, 0, 0, 0);
    }
    ((int4*)out)[i] = r.v;
}

// ---------------- transpose + cast: W (R x C fp32) -> Wt (C x R bf16) -----
__global__ void transpose_cast_kernel(const float* __restrict__ W,
                                      unsigned short* __restrict__ Wt,
                                      int R, int C) {
    __shared__ float t[32][33];
    int tx = threadIdx.x, ty = threadIdx.y;
    int c0 = blockIdx.x * 32, r0 = blockIdx.y * 32;
#pragma unroll
    for (int i = 0; i < 32; i += 8)
        t[ty + i][tx] = W[(size_t)(r0 + ty + i) * C + c0 + tx];
    __syncthreads();
#pragma unroll
    for (int i = 0; i < 32; i += 8)
        Wt[(size_t)(c0 + ty + i) * R + r0 + tx] = f2bf(t[tx][ty + i]);
}

// ---------------- 128x128 bf16 GEMM (m97 structure) ----------------
// A: M x K row-major bf16, Bt: N x K row-major bf16 (i.e. B transposed)
// MODE 0: C = bf16 (row*N+col), +bias
// MODE 1: C = fp32 (row*N+col), +bias
// MODE 2: K scatter: row->(b,m), col->(h,d): out[((b*16+h)*96+m)*64+d] bf16
// MODE 3: V scatter transposed: out[((b*16+h)*64+d)*96+m] bf16
static __device__ __forceinline__ void stage_tile(
    const unsigned short* __restrict__ G, int ldg, unsigned short* lds,
    int r0, int kt, int wv, int ln) {
    int rown = ln >> 2;
    int koff = (ln & 3) * 8;
#pragma unroll
    for (int r = 0; r < 2; ++r) {
        int cw = wv * 2 + r;
        const unsigned short* src =
            G + (size_t)(r0 + cw * 16 + rown) * ldg + kt + koff;
        __builtin_amdgcn_global_load_lds(
            (const __attribute__((address_space(1))) void*)src,
            (__attribute__((address_space(3))) void*)(lds + cw * 512),
            16, 0, 0);
    }
}

template <int MODE>
__global__ __launch_bounds__(256) void gemm_bt_kernel(
    const unsigned short* __restrict__ A, const unsigned short* __restrict__ Bt,
    const float* __restrict__ bias, void* __restrict__ Cout,
    int M, int N, int K) {
    __shared__ unsigned short As[128 * 32];
    __shared__ unsigned short Bs[128 * 32];
    const int tid = threadIdx.x, wv = tid >> 6, ln = tid & 63;
    const int numM = M >> 7, numN = N >> 7;
    int bid = blockIdx.x;
    const int nwg = numM * numN;
    if ((nwg & 7) == 0) { int cpx = nwg >> 3; bid = (bid & 7) * cpx + (bid >> 3); }
    const int mt = bid % numM, nt = bid / numM;
    const int m0 = mt << 7, n0 = nt << 7;
    const int wr = wv >> 1, wc = wv & 1;

    f32x4 acc[4][4] = {};
    for (int kt = 0; kt < K; kt += 32) {
        __syncthreads();
        stage_tile(A, K, As, m0, kt, wv, ln);
        stage_tile(Bt, K, Bs, n0, kt, wv, ln);
        __syncthreads();
        bf16x8 af[4], bfr[4];
#pragma unroll
        for (int i = 0; i < 4; ++i)
            af[i] = *(const bf16x8*)(As + (wr * 64 + i * 16 + (ln & 15)) * 32 +
                                     (ln >> 4) * 8);
#pragma unroll
        for (int j = 0; j < 4; ++j)
            bfr[j] = *(const bf16x8*)(Bs + (wc * 64 + j * 16 + (ln & 15)) * 32 +
                                      (ln >> 4) * 8);
#pragma unroll
        for (int i = 0; i < 4; ++i)
#pragma unroll
            for (int j = 0; j < 4; ++j)
                acc[i][j] = __builtin_amdgcn_mfma_f32_16x16x32_bf16(
                    af[i], bfr[j], acc[i][j], 0, 0, 0);
    }

    float bvals[4];
#pragma unroll
    for (int j = 0; j < 4; ++j)
        bvals[j] = bias[n0 + wc * 64 + j * 16 + (ln & 15)];

#pragma unroll
    for (int i = 0; i < 4; ++i) {
#pragma unroll
        for (int j = 0; j < 4; ++j) {
#pragma unroll
            for (int r = 0; r < 4; ++r) {
                int row = m0 + wr * 64 + i * 16 + (ln >> 4) * 4 + r;
                int col = n0 + wc * 64 + j * 16 + (ln & 15);
                float v = acc[i][j][r] + bvals[j];
                if constexpr (MODE == 0) {
                    ((unsigned short*)Cout)[(size_t)row * N + col] = f2bf(v);
                } else if constexpr (MODE == 1) {
                    ((float*)Cout)[(size_t)row * N + col] = v;
                } else {
                    if (row < BB * MM) {
                        int bb = row / MM, m = row - bb * MM;
                        int hh = col >> 6, d = col & 63;
                        if constexpr (MODE == 2)
                            ((unsigned short*)Cout)[((size_t)(bb * NH + hh) * MPAD + m) * HD + d] = f2bf(v);
                        else
                            ((unsigned short*)Cout)[((size_t)(bb * NH + hh) * HD + d) * MPAD + m] = f2bf(v);
                    }
                }
            }
        }
    }
}

// ---------------- fused attention: one wg per (64 q-rows, head) ----------
__global__ __launch_bounds__(256) void attn_kernel(
    const unsigned short* __restrict__ Q, const unsigned short* __restrict__ Kw,
    const unsigned short* __restrict__ Vt, const int* __restrict__ lengths,
    unsigned short* __restrict__ Out) {
    const int bh = blockIdx.y;
    const int b = bh >> 4, h = bh & 15;
    const int q0 = blockIdx.x * 64;
    const int tid = threadIdx.x, wv = tid >> 6, ln = tid & 63;
    const int len = lengths[b];

    __shared__ unsigned short Ks[96][72];   // K rows (m), cols d; padded
    __shared__ unsigned short Vs[64][104];  // V^T rows d, cols m; padded
    __shared__ unsigned short Ps[64][104];  // P rows q, cols m; padded

    // stage K (96x64) -> Ks and V^T (64x96) -> Vs
    {
        const unsigned short* Ksrc = Kw + (size_t)bh * (MPAD * HD);
        for (int c = tid; c < 768; c += 256) {
            int r = c >> 3, cc = (c & 7) * 8;
            *(int4*)(&Ks[r][cc]) = *(const int4*)(Ksrc + r * HD + cc);
        }
        const unsigned short* Vsrc = Vt + (size_t)bh * (HD * MPAD);
        for (int c = tid; c < 768; c += 256) {
            int r = c / 12, cc = (c % 12) * 8;
            *(int4*)(&Vs[r][cc]) = *(const int4*)(Vsrc + r * MPAD + cc);
        }
    }

    // Q fragments straight from global (each element read exactly once)
    const int qr = q0 + wv * 16 + (ln & 15);
    const unsigned short* qptr =
        Q + (size_t)(b * NN + qr) * EMB + h * HD + (ln >> 4) * 8;
    bf16x8 aq0 = *(const bf16x8*)(qptr);
    bf16x8 aq1 = *(const bf16x8*)(qptr + 32);

    __syncthreads();

    // S = Q K^T  (16 q-rows per wave x 96 cols)
    f32x4 s[6] = {};
#pragma unroll
    for (int t = 0; t < 6; ++t) {
        bf16x8 k0 = *(const bf16x8*)(&Ks[t * 16 + (ln & 15)][(ln >> 4) * 8]);
        bf16x8 k1 = *(const bf16x8*)(&Ks[t * 16 + (ln & 15)][32 + (ln >> 4) * 8]);
        s[t] = __builtin_amdgcn_mfma_f32_16x16x32_bf16(aq0, k0, s[t], 0, 0, 0);
        s[t] = __builtin_amdgcn_mfma_f32_16x16x32_bf16(aq1, k1, s[t], 0, 0, 0);
    }

    // masked softmax (rows = (ln>>4)*4+r in wave's 16-row block)
    const float scale = 0.125f;
    float mx[4] = {-1e30f, -1e30f, -1e30f, -1e30f};
#pragma unroll
    for (int t = 0; t < 6; ++t) {
        int m = t * 16 + (ln & 15);
#pragma unroll
        for (int r = 0; r < 4; ++r) {
            float v = (m < len) ? s[t][r] * scale : -1e30f;
            s[t][r] = v;
            mx[r] = fmaxf(mx[r], v);
        }
    }
#pragma unroll
    for (int d = 1; d < 16; d <<= 1)
#pragma unroll
        for (int r = 0; r < 4; ++r)
            mx[r] = fmaxf(mx[r], __shfl_xor(mx[r], d, 64));

    float sum[4] = {0.f, 0.f, 0.f, 0.f};
#pragma unroll
    for (int t = 0; t < 6; ++t)
#pragma unroll
        for (int r = 0; r < 4; ++r) {
            float p = __expf(s[t][r] - mx[r]);
            s[t][r] = p;
            sum[r] += p;
        }
#pragma unroll
    for (int d = 1; d < 16; d <<= 1)
#pragma unroll
        for (int r = 0; r < 4; ++r)
            sum[r] += __shfl_xor(sum[r], d, 64);

    // write unnormalized P (bf16) to LDS, own rows only.
    // Same-wave ds_write -> ds_read: DS pipe is in-order, no barrier needed.
#pragma unroll
    for (int t = 0; t < 6; ++t)
#pragma unroll
        for (int r = 0; r < 4; ++r)
            Ps[wv * 16 + (ln >> 4) * 4 + r][t * 16 + (ln & 15)] = f2bf(s[t][r]);

    // O = P V  (16 x 64 per wave)
    f32x4 o[4] = {};
#pragma unroll
    for (int ks = 0; ks < 3; ++ks) {
        bf16x8 pf = *(const bf16x8*)(&Ps[wv * 16 + (ln & 15)][ks * 32 + (ln >> 4) * 8]);
#pragma unroll
        for (int j = 0; j < 4; ++j) {
            bf16x8 vf = *(const bf16x8*)(&Vs[j * 16 + (ln & 15)][ks * 32 + (ln >> 4) * 8]);
            o[j] = __builtin_amdgcn_mfma_f32_16x16x32_bf16(pf, vf, o[j], 0, 0, 0);
        }
    }

    float rinv[4];
#pragma unroll
    for (int r = 0; r < 4; ++r) rinv[r] = 1.0f / sum[r];

#pragma unroll
    for (int j = 0; j < 4; ++j)
#pragma unroll
        for (int r = 0; r < 4; ++r) {
            int row = q0 + wv * 16 + (ln >> 4) * 4 + r;
            Out[(size_t)(b * NN + row) * EMB + h * HD + j * 16 + (ln & 15)] =
                f2bf(o[j][r] * rinv[r]);
        }
}

// ---------------- launch ----------------
extern "C" void kernel_launch(void* const* d_in, const int* in_sizes, int n_in,
                              void* d_out, int out_size, void* d_ws, size_t ws_size,
                              hipStream_t stream) {
    const float* x    = (const float*)d_in[0];
    const float* ctx  = (const float*)d_in[1];
    const unsigned char* cmask = (const unsigned char*)d_in[2];
    const float* Wq = (const float*)d_in[3];
    const float* bq = (const float*)d_in[4];
    const float* Wk = (const float*)d_in[5];
    const float* bk = (const float*)d_in[6];
    const float* Wv = (const float*)d_in[7];
    const float* bv = (const float*)d_in[8];
    const float* Wo = (const float*)d_in[9];
    const float* bo = (const float*)d_in[10];

    // ws layout (~75 MiB total). Qb lives in d_out's front half (64 MiB of
    // 128 MiB): dead until the final O-GEMM, which overwrites all of d_out
    // afterwards in stream order — deterministic under graph replay.
    char* ws = (char*)d_ws;
    unsigned short* Xbf   = (unsigned short*)(ws);              // 64 MiB; reused as attn_out
    unsigned short* Wq_t  = (unsigned short*)(ws + 67108864);   // 2 MiB
    unsigned short* Wo_t  = (unsigned short*)(ws + 69206016);   // 2 MiB
    unsigned short* Wk_t  = (unsigned short*)(ws + 71303168);   // 1.5 MiB
    unsigned short* Wv_t  = (unsigned short*)(ws + 72876032);   // 1.5 MiB
    unsigned short* Cbf   = (unsigned short*)(ws + 74448896);   // 640x768 bf16
    unsigned short* Kw    = (unsigned short*)(ws + 75431936);   // 128x96x64 bf16
    unsigned short* Vtw   = (unsigned short*)(ws + 77004800);   // 128x64x96 bf16
    int* lengths          = (int*)(ws + 78577664);
    unsigned short* Qb    = (unsigned short*)d_out;             // 64 MiB scratch

    mask_lengths_kernel<<<1, 64, 0, stream>>>(cmask, lengths);
    cast_f32_to_bf16<<<2048, 256, 0, stream>>>(x, Xbf, (BB * NN * EMB) / 8);
    cast_ctx_kernel<<<240, 256, 0, stream>>>(ctx, Cbf);
    transpose_cast_kernel<<<dim3(32, 32), dim3(32, 8), 0, stream>>>(Wq, Wq_t, 1024, 1024);
    transpose_cast_kernel<<<dim3(32, 24), dim3(32, 8), 0, stream>>>(Wk, Wk_t, 768, 1024);
    transpose_cast_kernel<<<dim3(32, 24), dim3(32, 8), 0, stream>>>(Wv, Wv_t, 768, 1024);
    transpose_cast_kernel<<<dim3(32, 32), dim3(32, 8), 0, stream>>>(Wo, Wo_t, 1024, 1024);
    hipMemsetAsync(Kw, 0, 2 * 1572864, stream); // zero K + V^T padded buffers

    gemm_bt_kernel<0><<<2048, 256, 0, stream>>>(Xbf, Wq_t, bq, Qb, 32768, 1024, 1024);
    gemm_bt_kernel<2><<<40, 256, 0, stream>>>(Cbf, Wk_t, bk, Kw, 640, 1024, 768);
    gemm_bt_kernel<3><<<40, 256, 0, stream>>>(Cbf, Wv_t, bv, Vtw, 640, 1024, 768);

    attn_kernel<<<dim3(64, 128), 256, 0, stream>>>(Qb, Kw, Vtw, lengths, Xbf);

    gemm_bt_kernel<1><<<2048, 256, 0, stream>>>(Xbf, Wo_t, bo, d_out, 32768, 1024, 1024);
}